// Round 3
// baseline (132.590 us; speedup 1.0000x reference)
//
#include <hip/hip_runtime.h>

// CRF-RNN mean-field, 2 iterations, N=8192 (32x16x16), C=4.
// Spatial attention is EXACTLY separable (regular grid Gaussian) -> 3 dense 1-D convs.
// Only the bilateral attention stays N^2 (split-K over j).
// Per iteration: conv_dw (softmax + conv_d + conv_w) -> bilat_pass1 (N^2) -> pass2
// (split-K reduce + conv_h + normalize + 4x4 matmuls + unary add).

#define HH 32
#define WW 16
#define DDD 16
#define NN (HH * WW * DDD)    // 8192
#define TILE 128              // j-records per LDS tile in bilat_pass1
#define L2E 1.4426950408889634f
#define C18 (L2E / 18.0f)     // spatial: exp(-d^2/(2*3^2)) == exp2(-d^2*C18)

#if __has_builtin(__builtin_amdgcn_exp2f)
#define EXP2(x) __builtin_amdgcn_exp2f(x)
#else
#define EXP2(x) exp2f(x)
#endif

// bilateral features pre-scaled by sqrt(log2 e) so exp(logit) == exp2(scaled logit)
__device__ __forceinline__ void bilat_feats(int n, const float* __restrict__ rgb,
                                            float fb[6], float& nhb)
{
    const float SQL2E = 1.2011224087864498f;  // sqrt(log2(e))
    int h = n >> 8;          // / (16*16)
    int r = n & 255;
    int w = r >> 4;
    int d = r & 15;
    const float sb = SQL2E / 8.0f;   // THETA_ALPHA
    const float sc = SQL2E / 0.5f;   // THETA_BETA
    fb[0] = (float)(h + 1) * sb;
    fb[1] = (float)(w + 1) * sb;
    fb[2] = (float)(d + 1) * sb;
    fb[3] = rgb[3 * n + 0] * sc;
    fb[4] = rgb[3 * n + 1] * sc;
    fb[5] = rgb[3 * n + 2] * sc;
    nhb = -0.5f * (fb[0] * fb[0] + fb[1] * fb[1] + fb[2] * fb[2] +
                   fb[3] * fb[3] + fb[4] * fb[4] + fb[5] * fb[5]);
}

// Per h-slab: softmax(q) -> sm (global), then dense 1-D Gaussian conv along D then W.
__global__ __launch_bounds__(256) void conv_dw(
    const float* __restrict__ qin,   // [N][4]
    float* __restrict__ smout,       // [N][4]
    float* __restrict__ tmp)         // [N][4] spatial partial (d,w convolved)
{
    int h = blockIdx.x;
    int s = threadIdx.x;             // s = w*16 + d
    int i = h * 256 + s;

    float4 q = *((const float4*)(qin + 4 * i));
    float m = fmaxf(fmaxf(q.x, q.y), fmaxf(q.z, q.w));
    float e0 = EXP2((q.x - m) * L2E), e1 = EXP2((q.y - m) * L2E);
    float e2 = EXP2((q.z - m) * L2E), e3 = EXP2((q.w - m) * L2E);
    float rs = 1.0f / (e0 + e1 + e2 + e3);
    float4 sm = make_float4(e0 * rs, e1 * rs, e2 * rs, e3 * rs);
    *((float4*)(smout + 4 * i)) = sm;

    __shared__ float A[256][4];
    __shared__ float B[256][4];
    *((float4*)A[s]) = sm;
    __syncthreads();

    int w = s >> 4, d = s & 15;
    float t0 = 0, t1 = 0, t2 = 0, t3 = 0;
    #pragma unroll
    for (int dp = 0; dp < DDD; ++dp) {
        float dd = (float)(d - dp);
        float k = EXP2(-dd * dd * C18);
        const float4 v = *((const float4*)A[w * 16 + dp]);
        t0 = fmaf(k, v.x, t0); t1 = fmaf(k, v.y, t1);
        t2 = fmaf(k, v.z, t2); t3 = fmaf(k, v.w, t3);
    }
    *((float4*)B[s]) = make_float4(t0, t1, t2, t3);
    __syncthreads();

    float u0 = 0, u1 = 0, u2 = 0, u3 = 0;
    #pragma unroll
    for (int wp = 0; wp < WW; ++wp) {
        float dw = (float)(w - wp);
        float k = EXP2(-dw * dw * C18);
        const float4 v = *((const float4*)B[wp * 16 + d]);
        u0 = fmaf(k, v.x, u0); u1 = fmaf(k, v.y, u1);
        u2 = fmaf(k, v.z, u2); u3 = fmaf(k, v.w, u3);
    }
    *((float4*)(tmp + 4 * i)) = make_float4(u0, u1, u2, u3);
}

// N^2 bilateral numerators, 2 i-rows per thread, split-K over j.
__global__ __launch_bounds__(256) void bilat_pass1(
    const float* __restrict__ sm,    // [N][4] softmax(q)
    const float* __restrict__ rgb,   // [N][3]
    float* __restrict__ part,        // [kSplit][N][4]
    int kSplit)
{
    const int NBI2 = NN / 512;       // 16 i-tiles (512 i per block)
    int kc = blockIdx.x / NBI2;
    int ib = blockIdx.x - kc * NBI2;
    int tid = threadIdx.x;
    int i0 = ib * 512 + tid;
    int i1 = i0 + 256;
    int JC = NN / kSplit;
    int j0 = kc * JC;

    float fA[6], fB[6], nA, nB;
    bilat_feats(i0, rgb, fA, nA);
    bilat_feats(i1, rgb, fB, nB);

    // 12-float (48B) records: 16B-aligned, 8-way (not 32-way) staging conflicts
    __shared__ float recs[TILE][12];

    float a0 = 0, a1 = 0, a2 = 0, a3 = 0;
    float b0 = 0, b1 = 0, b2 = 0, b3 = 0;

    for (int jt = 0; jt < JC; jt += TILE) {
        int tc = JC - jt; if (tc > TILE) tc = TILE;
        __syncthreads();
        if (tid < tc) {
            int j = j0 + jt + tid;
            float fj[6], nj;
            bilat_feats(j, rgb, fj, nj);
            float4 s = *((const float4*)(sm + 4 * j));
            *((float4*)&recs[tid][0]) = make_float4(fj[0], fj[1], fj[2], fj[3]);
            *((float4*)&recs[tid][4]) = make_float4(fj[4], fj[5], nj, 0.0f);
            *((float4*)&recs[tid][8]) = s;
        }
        __syncthreads();

        #pragma unroll 4
        for (int jj = 0; jj < tc; ++jj) {
            const float4 r0 = *((const float4*)&recs[jj][0]);
            const float4 r1 = *((const float4*)&recs[jj][4]);
            const float4 s  = *((const float4*)&recs[jj][8]);
            float gA = nA + r1.z;
            gA = fmaf(fA[0], r0.x, gA);
            gA = fmaf(fA[1], r0.y, gA);
            gA = fmaf(fA[2], r0.z, gA);
            gA = fmaf(fA[3], r0.w, gA);
            gA = fmaf(fA[4], r1.x, gA);
            gA = fmaf(fA[5], r1.y, gA);
            float gB = nB + r1.z;
            gB = fmaf(fB[0], r0.x, gB);
            gB = fmaf(fB[1], r0.y, gB);
            gB = fmaf(fB[2], r0.z, gB);
            gB = fmaf(fB[3], r0.w, gB);
            gB = fmaf(fB[4], r1.x, gB);
            gB = fmaf(fB[5], r1.y, gB);
            float wA = EXP2(gA);
            float wB = EXP2(gB);
            a0 = fmaf(wA, s.x, a0); a1 = fmaf(wA, s.y, a1);
            a2 = fmaf(wA, s.z, a2); a3 = fmaf(wA, s.w, a3);
            b0 = fmaf(wB, s.x, b0); b1 = fmaf(wB, s.y, b1);
            b2 = fmaf(wB, s.z, b2); b3 = fmaf(wB, s.w, b3);
        }
    }

    float4* p = (float4*)(part + (size_t)kc * NN * 4);
    p[i0] = make_float4(a0, a1, a2, a3);
    p[i1] = make_float4(b0, b1, b2, b3);
}

// Reduce split-K bilateral partials, conv along H (finishes spatial), normalize
// (denominator == channel-sum since sum_c sm == 1), 4x4 matmuls, add unaries.
__global__ __launch_bounds__(256) void pass2(
    const float* __restrict__ part, int kSplit,
    const float* __restrict__ tmp,   // [N][4] d,w-convolved sm
    const float* __restrict__ u,
    const float* __restrict__ sk, const float* __restrict__ bk,
    const float* __restrict__ cm,
    float* __restrict__ qout)
{
    int h = blockIdx.x;
    int s = threadIdx.x;
    int i = h * 256 + s;

    float bl[4] = {0, 0, 0, 0};
    for (int kc = 0; kc < kSplit; ++kc) {
        const float4 p = *((const float4*)(part + ((size_t)kc * NN + i) * 4));
        bl[0] += p.x; bl[1] += p.y; bl[2] += p.z; bl[3] += p.w;
    }

    float sp[4] = {0, 0, 0, 0};
    #pragma unroll
    for (int hp = 0; hp < HH; ++hp) {
        float dh = (float)(h - hp);
        float k = EXP2(-dh * dh * C18);
        const float4 v = *((const float4*)(tmp + 4 * (hp * 256 + s)));
        sp[0] = fmaf(k, v.x, sp[0]); sp[1] = fmaf(k, v.y, sp[1]);
        sp[2] = fmaf(k, v.z, sp[2]); sp[3] = fmaf(k, v.w, sp[3]);
    }

    float rs = 1.0f / (sp[0] + sp[1] + sp[2] + sp[3]);
    float rb = 1.0f / (bl[0] + bl[1] + bl[2] + bl[3]);
    float so[4], bo[4];
    #pragma unroll
    for (int c = 0; c < 4; ++c) { so[c] = sp[c] * rs; bo[c] = bl[c] * rb; }

    float msg[4];
    #pragma unroll
    for (int c = 0; c < 4; ++c) {
        float m = 0.0f;
        #pragma unroll
        for (int d = 0; d < 4; ++d)
            m += sk[c * 4 + d] * so[d] + bk[c * 4 + d] * bo[d];
        msg[c] = m;
    }
    #pragma unroll
    for (int c = 0; c < 4; ++c) {
        float pw = 0.0f;
        #pragma unroll
        for (int d = 0; d < 4; ++d) pw += cm[c * 4 + d] * msg[d];
        qout[4 * i + c] = u[4 * i + c] + pw;
    }
}

extern "C" void kernel_launch(void* const* d_in, const int* in_sizes, int n_in,
                              void* d_out, int out_size, void* d_ws, size_t ws_size,
                              hipStream_t stream)
{
    const float* u   = (const float*)d_in[0];
    const float* rgb = (const float*)d_in[1];
    const float* sk  = (const float*)d_in[2];
    const float* bk  = (const float*)d_in[3];
    const float* cm  = (const float*)d_in[4];
    float* out = (float*)d_out;

    // workspace: part[kSplit][N][4] | sm[N][4] | tmp[N][4] | qbuf[N][4]
    int kSplit = 128;
    while (kSplit > 1 &&
           ((size_t)kSplit * NN * 4 + 3 * (size_t)NN * 4) * sizeof(float) > ws_size)
        kSplit >>= 1;

    float* part = (float*)d_ws;
    float* smP  = part + (size_t)kSplit * NN * 4;
    float* tmpP = smP + (size_t)NN * 4;
    float* qbuf = tmpP + (size_t)NN * 4;

    dim3 blk(256);
    dim3 gS(HH);                       // 32 blocks, one per h-slab
    dim3 g1((NN / 512) * kSplit);      // 16 i-tiles * kSplit

    // iteration 1 (q = u)
    conv_dw<<<gS, blk, 0, stream>>>(u, smP, tmpP);
    bilat_pass1<<<g1, blk, 0, stream>>>(smP, rgb, part, kSplit);
    pass2<<<gS, blk, 0, stream>>>(part, kSplit, tmpP, u, sk, bk, cm, qbuf);
    // iteration 2
    conv_dw<<<gS, blk, 0, stream>>>(qbuf, smP, tmpP);
    bilat_pass1<<<g1, blk, 0, stream>>>(smP, rgb, part, kSplit);
    pass2<<<gS, blk, 0, stream>>>(part, kSplit, tmpP, u, sk, bk, cm, out);
}